// Round 6
// baseline (833.793 us; speedup 1.0000x reference)
//
#include <hip/hip_runtime.h>
#include <hip/hip_bf16.h>
#include <stdint.h>

#define B_ 4
#define S_ 2048
#define H_ 1024
#define I_ 4096
#define E_ 8
#define CAP 640
#define NTOK (B_*S_)            // 8192
#define NBE  (B_*E_)            // 32

typedef _Float16 f16;
typedef f16 f16x8 __attribute__((ext_vector_type(8)));
typedef float f32x4 __attribute__((ext_vector_type(4)));

// workspace layout (bytes)
#define OFF_LOGITS 0u                          // 65536 f32
#define OFF_TOPKI  (256u*1024u)                // 20480 int
#define OFF_TOPKW  (OFF_TOPKI + 128u*1024u)    // 20480 f32
#define OFF_COUNTS (OFF_TOPKW + 128u*1024u)    // 8192 f32
#define OFF_SCAL   (OFF_COUNTS + 64u*1024u)    // 16 f32
#define OFF_XH     (1u<<20)                    // 8192*1024 f16   (16.8 MB)
#define OFF_WT     (18u<<20)                   // 8*4096*1024 f16 (67.1 MB) — w1t then w2t (reused)
#define OFF_MID    (86u<<20)                   // 20480*4096 f16  (167.8 MB) → high-water ~254 MB

__device__ __forceinline__ void gl_lds16(const void* g, void* l) {
    __builtin_amdgcn_global_load_lds(
        (const __attribute__((address_space(1))) uint32_t*)g,
        (__attribute__((address_space(3))) uint32_t*)l, 16, 0, 0);
}

// ---------------------------------------------------------------- router ----
// NOTE: summation order is frozen — top-k selection depends on exact fp32
// logit ordering near capacity boundaries. Do not restructure this reduce.
__global__ void k_router(const float* __restrict__ x, const float* __restrict__ rw,
                         float* __restrict__ logits, float* __restrict__ scal) {
    __shared__ float rwt[E_ * H_];
    __shared__ float part[4][9];
    int tid = threadIdx.x;
    for (int i = tid; i < E_ * H_; i += 256) {
        int h = i >> 3, e = i & 7;
        rwt[e * H_ + h] = rw[i];
    }
    __syncthreads();
    int w = tid >> 6, lane = tid & 63;
    int t = blockIdx.x * 4 + w;
    const float* xr = x + (size_t)t * H_;
    float acc[E_];
#pragma unroll
    for (int e = 0; e < E_; ++e) acc[e] = 0.f;
    for (int it = 0; it < H_ / 64; ++it) {
        int h = lane + it * 64;
        float xv = xr[h];
#pragma unroll
        for (int e = 0; e < E_; ++e) acc[e] += xv * rwt[e * H_ + h];
    }
#pragma unroll
    for (int off = 32; off > 0; off >>= 1)
#pragma unroll
        for (int e = 0; e < E_; ++e) acc[e] += __shfl_down(acc[e], off);
    if (lane == 0) {
        int b = t >> 11, s = t & 2047;
        float m = acc[0];
#pragma unroll
        for (int e = 1; e < E_; ++e) m = fmaxf(m, acc[e]);
        float z = 0.f, ps = 0.f;
        float p[E_];
#pragma unroll
        for (int e = 0; e < E_; ++e) {
            logits[(size_t)((b << 3) + e) * S_ + s] = acc[e];
            z += acc[e] * acc[e];
            p[e] = expf(acc[e] - m);
            ps += p[e];
        }
        part[w][0] = z;
#pragma unroll
        for (int e = 0; e < E_; ++e) part[w][1 + e] = p[e] / ps;
    }
    __syncthreads();
    if (tid < 9) {
        float v = part[0][tid] + part[1][tid] + part[2][tid] + part[3][tid];
        atomicAdd(&scal[tid], v);
    }
}

// ----------------------------------------------------------------- top-k ----
__global__ void __launch_bounds__(1024) k_topk(const float* __restrict__ logits,
                                               int* __restrict__ tki,
                                               float* __restrict__ tkw,
                                               float* __restrict__ counts) {
    int be = blockIdx.x;
    const float* row = logits + (size_t)be * S_;
    __shared__ unsigned long long keys[S_];
    __shared__ float wpart[16];
    __shared__ float stot;
    int tid = threadIdx.x;
    for (int i = tid; i < S_; i += 1024) {
        unsigned u = __float_as_uint(row[i]);
        u = (u & 0x80000000u) ? ~u : (u | 0x80000000u);
        keys[i] = ((unsigned long long)u << 32) | (unsigned)(~i);
    }
    __syncthreads();
    for (int k = 2; k <= S_; k <<= 1) {
        for (int j = k >> 1; j > 0; j >>= 1) {
#pragma unroll
            for (int base = 0; base < S_; base += 1024) {
                int i = base + tid;
                int ixj = i ^ j;
                if (ixj > i) {
                    unsigned long long a = keys[i], b = keys[ixj];
                    bool up = ((i & k) == 0);
                    bool sw = up ? (a < b) : (a > b);
                    if (sw) { keys[i] = b; keys[ixj] = a; }
                }
            }
            __syncthreads();
        }
    }
    int idx0 = (int)(~(unsigned)(keys[0] & 0xFFFFFFFFu));
    float vmax = row[idx0];
    int myidx = 0; float ex = 0.f;
    if (tid < CAP) {
        myidx = (int)(~(unsigned)(keys[tid] & 0xFFFFFFFFu));
        ex = expf(row[myidx] - vmax);
    }
    float v = ex;
#pragma unroll
    for (int off = 32; off > 0; off >>= 1) v += __shfl_down(v, off);
    if ((tid & 63) == 0) wpart[tid >> 6] = v;
    __syncthreads();
    if (tid == 0) {
        float s = 0.f;
#pragma unroll
        for (int i = 0; i < 16; ++i) s += wpart[i];
        stot = s;
    }
    __syncthreads();
    if (tid < CAP) {
        tki[be * CAP + tid] = myidx;
        tkw[be * CAP + tid] = ex / stot;
        atomicAdd(&counts[(be >> 3) * S_ + myidx], 1.0f);
    }
}

// ------------------------------------------------------------ conversions ---
__global__ void k_cvt_x(const float* __restrict__ in, f16* __restrict__ out) {
    size_t i = ((size_t)blockIdx.x * 256 + threadIdx.x) << 3;
    float4 a = *(const float4*)(in + i);
    float4 b = *(const float4*)(in + i + 4);
    f16x8 o = { (f16)a.x, (f16)a.y, (f16)a.z, (f16)a.w,
                (f16)b.x, (f16)b.y, (f16)b.z, (f16)b.w };
    *(f16x8*)(out + i) = o;
}

// in: [E][R][C] f32 → out: [E][C][R] f16
template<int R, int C>
__global__ void __launch_bounds__(256) k_transpose(const float* __restrict__ in,
                                                   f16* __restrict__ out) {
    __shared__ f16 t[64][68];
    int e = blockIdx.z;
    const float* ine = in + (size_t)e * R * C;
    f16* oute = out + (size_t)e * R * C;
    int c0 = blockIdx.x << 6, r0 = blockIdx.y << 6;
    int tx = threadIdx.x & 15, ty = threadIdx.x >> 4;
#pragma unroll
    for (int p = 0; p < 4; ++p) {
        int r = ty + p * 16;
        float4 v = *(const float4*)(ine + (size_t)(r0 + r) * C + c0 + tx * 4);
        t[tx * 4 + 0][r] = (f16)v.x;
        t[tx * 4 + 1][r] = (f16)v.y;
        t[tx * 4 + 2][r] = (f16)v.z;
        t[tx * 4 + 3][r] = (f16)v.w;
    }
    __syncthreads();
#pragma unroll
    for (int p = 0; p < 4; ++p) {
        int c = ty + p * 16;
        *(ushort4*)(oute + (size_t)(c0 + c) * R + r0 + tx * 4) =
            *(const ushort4*)&t[c][tx * 4];
    }
}

// ============================ GEMM core geometry =============================
// 512 thr = 8 waves; wm = w>>2 (2 M-halves), wn = w&3 (4 N-quarters).
// Tile 256x256, BK=32, per-wave C = 128x64 (mi 0..7, ni 0..3).
// LDS: FOUR K-tile buffers, A[4][256][32] + B[4][256][32] f16 = 128 KB.
// Swizzle: 16B chunk slot s of row r holds global chunk s ^ (r&3)
//   (staged via per-lane pre-swizzled global source; LDS dest linear,
//    wave-uniform base + lane*16B). Conflict-free (round-5 measured 0).
// Pipeline (T4, counted): iter t computes buf[t&3], stages tile t+3 into
// buf[(t+3)&3]; gate = vmcnt(8) (tiles t+2,t+3 stay in flight — NEVER 0)
// + one raw s_barrier per tile. Cover ≈ 2 K-tiles (~700cy) > HBM latency.
// WAR safe: buf[(t+3)&3] last read in iter t-1, barrier-separated.

#define MFMA4(MI, A) \
    acc[MI][0] = __builtin_amdgcn_mfma_f32_16x16x32_f16(A, bf0, acc[MI][0], 0, 0, 0); \
    acc[MI][1] = __builtin_amdgcn_mfma_f32_16x16x32_f16(A, bf1, acc[MI][1], 0, 0, 0); \
    acc[MI][2] = __builtin_amdgcn_mfma_f32_16x16x32_f16(A, bf2, acc[MI][2], 0, 0, 0); \
    acc[MI][3] = __builtin_amdgcn_mfma_f32_16x16x32_f16(A, bf3, acc[MI][3], 0, 0, 0);

// ---------------------------------------------------------- GEMM1 (+SiLU) ---
__global__ void __launch_bounds__(512, 2) k_gemm1(const f16* __restrict__ xh,
                                                  const f16* __restrict__ w1t,
                                                  const int* __restrict__ tki,
                                                  f16* __restrict__ mid) {
    __shared__ f16 Ab[4 * 8192];   // 64 KB
    __shared__ f16 Bb[4 * 8192];   // 64 KB
    int bid = blockIdx.x;
    int orig = (bid & 7) * 160 + (bid >> 3);   // XCD chunk: 160 blocks = 1 expert
    int ct = orig & 15;
    int g = orig >> 4;                         // 0..79
    int mt = g % 10;
    int e = g / 10;
    int n0 = ct << 8;
    const f16* w1e = w1t + ((size_t)e << 22);
    int tid = threadIdx.x;
    int w = tid >> 6, l = tid & 63;
    int wm = w >> 2, wn = w & 3;

    // staging: lane covers row = tid>>2 (and +128), slot = tid&3,
    // global chunk gch = slot ^ (row&3)
    int srow = tid >> 2;
    int gch = (tid & 3) ^ (srow & 3);
    int geA0 = mt * 256 + srow;
    int geA1 = geA0 + 128;
    int bb0 = geA0 / 640, cc0 = geA0 - bb0 * 640;
    int bb1 = geA1 / 640, cc1 = geA1 - bb1 * 640;
    int tok0 = tki[((bb0 << 3) + e) * 640 + cc0];
    int tok1 = tki[((bb1 << 3) + e) * 640 + cc1];
    const f16* aS0 = xh + ((size_t)((bb0 << 11) + tok0) << 10) + (gch << 3);
    const f16* aS1 = xh + ((size_t)((bb1 << 11) + tok1) << 10) + (gch << 3);
    const f16* bS0 = w1e + ((size_t)(n0 + srow) << 10) + (gch << 3);
    const f16* bS1 = w1e + ((size_t)(n0 + 128 + srow) << 10) + (gch << 3);
    int dst0 = w << 9;             // wave-uniform LDS dest (HW adds lane*16B)
    int dst1 = 4096 + (w << 9);

    int fr = l & 15, c4 = l >> 4;
    int slotR = (c4 ^ (fr & 3)) << 3;
    int aoff = ((wm << 7) + fr) * 32 + slotR;   // + mi*512
    int boff = ((wn << 6) + fr) * 32 + slotR;   // + ni*512

    f32x4 acc[8][4];
#pragma unroll
    for (int mi = 0; mi < 8; ++mi)
#pragma unroll
        for (int ni = 0; ni < 4; ++ni) acc[mi][ni] = (f32x4){0.f, 0.f, 0.f, 0.f};

    // prologue: stage tiles 0,1,2 (order per tile: A0,A1,B0,B1)
#pragma unroll
    for (int pt = 0; pt < 3; ++pt) {
        int ko = pt << 5;
        gl_lds16(aS0 + ko, Ab + (pt << 13) + dst0);
        gl_lds16(aS1 + ko, Ab + (pt << 13) + dst1);
        gl_lds16(bS0 + ko, Bb + (pt << 13) + dst0);
        gl_lds16(bS1 + ko, Bb + (pt << 13) + dst1);
    }
    asm volatile("s_waitcnt vmcnt(8)" ::: "memory");   // tile 0 landed
    __builtin_amdgcn_s_barrier();

    const int NT = H_ / 32;   // 32
    for (int t = 0; t < NT; ++t) {
        const f16* Ac = Ab + ((t & 3) << 13);
        const f16* Bc = Bb + ((t & 3) << 13);
        f16* An = Ab + (((t + 3) & 3) << 13);
        f16* Bn = Bb + (((t + 3) & 3) << 13);
        int kt = t + 3; if (kt > NT - 1) kt = NT - 1;
        int ko = kt << 5;
        // phase 0: B frags + A mi0-3; stage next A
        f16x8 bf0 = *(const f16x8*)(Bc + boff);
        f16x8 bf1 = *(const f16x8*)(Bc + boff + 512);
        f16x8 bf2 = *(const f16x8*)(Bc + boff + 1024);
        f16x8 bf3 = *(const f16x8*)(Bc + boff + 1536);
        f16x8 a0 = *(const f16x8*)(Ac + aoff);
        f16x8 a1 = *(const f16x8*)(Ac + aoff + 512);
        f16x8 a2 = *(const f16x8*)(Ac + aoff + 1024);
        f16x8 a3 = *(const f16x8*)(Ac + aoff + 1536);
        gl_lds16(aS0 + ko, An + dst0);
        gl_lds16(aS1 + ko, An + dst1);
        __builtin_amdgcn_s_setprio(1);
        MFMA4(0, a0) MFMA4(1, a1) MFMA4(2, a2) MFMA4(3, a3)
        __builtin_amdgcn_s_setprio(0);
        // phase 1: A mi4-7; stage next B
        a0 = *(const f16x8*)(Ac + aoff + 2048);
        a1 = *(const f16x8*)(Ac + aoff + 2560);
        a2 = *(const f16x8*)(Ac + aoff + 3072);
        a3 = *(const f16x8*)(Ac + aoff + 3584);
        gl_lds16(bS0 + ko, Bn + dst0);
        gl_lds16(bS1 + ko, Bn + dst1);
        __builtin_amdgcn_s_setprio(1);
        MFMA4(4, a0) MFMA4(5, a1) MFMA4(6, a2) MFMA4(7, a3)
        __builtin_amdgcn_s_setprio(0);
        asm volatile("s_waitcnt vmcnt(8)" ::: "memory");   // tile t+1 ready
        __builtin_amdgcn_s_barrier();
    }

    // epilogue: SiLU + f16 store to mid
    int rq4 = c4 << 2;
#pragma unroll
    for (int mi = 0; mi < 8; ++mi) {
        int rbase = (wm << 7) + mi * 16 + rq4;
#pragma unroll
        for (int q = 0; q < 4; ++q) {
            int ge = mt * 256 + rbase + q;
            int bb = ge / 640;
            int cc = ge - bb * 640;
            size_t flat = (size_t)(((bb << 3) + e) * 640 + cc);
            f16* mrow = mid + (flat << 12) + n0 + (wn << 6) + fr;
#pragma unroll
            for (int ni = 0; ni < 4; ++ni) {
                float v = acc[mi][ni][q];
                v = v / (1.f + expf(-v));
                mrow[ni * 16] = (f16)v;
            }
        }
    }
}

// ------------------------------------------- GEMM2 + weighted atomic scatter
// K split 4 ways (ks); partials combined via f32 atomicAdd.
__global__ void __launch_bounds__(512, 2) k_gemm2(const f16* __restrict__ mid,
                                                  const f16* __restrict__ w2t,
                                                  const int* __restrict__ tki,
                                                  const float* __restrict__ tkw,
                                                  float* __restrict__ out) {
    __shared__ f16 Ab[4 * 8192];
    __shared__ f16 Bb[4 * 8192];
    __shared__ int   rowOffS[256];
    __shared__ float wtsS[256];
    int bid = blockIdx.x;
    int orig = (bid & 7) * 160 + (bid >> 3);
    int ct = orig & 3;
    int ks = (orig >> 2) & 3;
    int g = orig >> 4;
    int mt = g % 10;
    int e = g / 10;
    int n0 = ct << 8;
    const f16* w2e = w2t + ((size_t)e << 22);
    int tid = threadIdx.x;
    int w = tid >> 6, l = tid & 63;
    int wm = w >> 2, wn = w & 3;

    if (tid < 256) {
        int ge = mt * 256 + tid;
        int bb = ge / 640;
        int cc = ge - bb * 640;
        int flat = ((bb << 3) + e) * 640 + cc;
        int tok = tki[flat];
        rowOffS[tid] = ((bb << 11) + tok) << 10;
        wtsS[tid] = tkw[flat];
    }

    int srow = tid >> 2;
    int gch = (tid & 3) ^ (srow & 3);
    int geA0 = mt * 256 + srow;
    int geA1 = geA0 + 128;
    int bb0 = geA0 / 640, cc0 = geA0 - bb0 * 640;
    int bb1 = geA1 / 640, cc1 = geA1 - bb1 * 640;
    size_t fl0 = (size_t)(((bb0 << 3) + e) * 640 + cc0);
    size_t fl1 = (size_t)(((bb1 << 3) + e) * 640 + cc1);
    const f16* aS0 = mid + (fl0 << 12) + (ks << 10) + (gch << 3);
    const f16* aS1 = mid + (fl1 << 12) + (ks << 10) + (gch << 3);
    const f16* bS0 = w2e + ((size_t)(n0 + srow) << 12) + (ks << 10) + (gch << 3);
    const f16* bS1 = w2e + ((size_t)(n0 + 128 + srow) << 12) + (ks << 10) + (gch << 3);
    int dst0 = w << 9;
    int dst1 = 4096 + (w << 9);

    int fr = l & 15, c4 = l >> 4;
    int slotR = (c4 ^ (fr & 3)) << 3;
    int aoff = ((wm << 7) + fr) * 32 + slotR;
    int boff = ((wn << 6) + fr) * 32 + slotR;

    f32x4 acc[8][4];
#pragma unroll
    for (int mi = 0; mi < 8; ++mi)
#pragma unroll
        for (int ni = 0; ni < 4; ++ni) acc[mi][ni] = (f32x4){0.f, 0.f, 0.f, 0.f};

#pragma unroll
    for (int pt = 0; pt < 3; ++pt) {
        int ko = pt << 5;
        gl_lds16(aS0 + ko, Ab + (pt << 13) + dst0);
        gl_lds16(aS1 + ko, Ab + (pt << 13) + dst1);
        gl_lds16(bS0 + ko, Bb + (pt << 13) + dst0);
        gl_lds16(bS1 + ko, Bb + (pt << 13) + dst1);
    }
    asm volatile("s_waitcnt vmcnt(8)" ::: "memory");
    __builtin_amdgcn_s_barrier();

    const int NT = 32;   // 1024 K per ks-slice
    for (int t = 0; t < NT; ++t) {
        const f16* Ac = Ab + ((t & 3) << 13);
        const f16* Bc = Bb + ((t & 3) << 13);
        f16* An = Ab + (((t + 3) & 3) << 13);
        f16* Bn = Bb + (((t + 3) & 3) << 13);
        int kt = t + 3; if (kt > NT - 1) kt = NT - 1;
        int ko = kt << 5;
        f16x8 bf0 = *(const f16x8*)(Bc + boff);
        f16x8 bf1 = *(const f16x8*)(Bc + boff + 512);
        f16x8 bf2 = *(const f16x8*)(Bc + boff + 1024);
        f16x8 bf3 = *(const f16x8*)(Bc + boff + 1536);
        f16x8 a0 = *(const f16x8*)(Ac + aoff);
        f16x8 a1 = *(const f16x8*)(Ac + aoff + 512);
        f16x8 a2 = *(const f16x8*)(Ac + aoff + 1024);
        f16x8 a3 = *(const f16x8*)(Ac + aoff + 1536);
        gl_lds16(aS0 + ko, An + dst0);
        gl_lds16(aS1 + ko, An + dst1);
        __builtin_amdgcn_s_setprio(1);
        MFMA4(0, a0) MFMA4(1, a1) MFMA4(2, a2) MFMA4(3, a3)
        __builtin_amdgcn_s_setprio(0);
        a0 = *(const f16x8*)(Ac + aoff + 2048);
        a1 = *(const f16x8*)(Ac + aoff + 2560);
        a2 = *(const f16x8*)(Ac + aoff + 3072);
        a3 = *(const f16x8*)(Ac + aoff + 3584);
        gl_lds16(bS0 + ko, Bn + dst0);
        gl_lds16(bS1 + ko, Bn + dst1);
        __builtin_amdgcn_s_setprio(1);
        MFMA4(4, a0) MFMA4(5, a1) MFMA4(6, a2) MFMA4(7, a3)
        __builtin_amdgcn_s_setprio(0);
        asm volatile("s_waitcnt vmcnt(8)" ::: "memory");
        __builtin_amdgcn_s_barrier();
    }

    int rq4 = c4 << 2;
#pragma unroll
    for (int mi = 0; mi < 8; ++mi) {
        int rbase = (wm << 7) + mi * 16 + rq4;
#pragma unroll
        for (int q = 0; q < 4; ++q) {
            int row = rbase + q;
            int ro = rowOffS[row] + n0 + (wn << 6) + fr;
            float wg = wtsS[row];
#pragma unroll
            for (int ni = 0; ni < 4; ++ni) {
                atomicAdd(&out[ro + ni * 16], acc[mi][ni][q] * wg);
            }
        }
    }
}

// ------------------------------------------------- normalize + loss ---------
__global__ void k_final(float* __restrict__ out, const float* __restrict__ counts,
                        const float* __restrict__ scal, float* __restrict__ loss_out) {
    size_t gid = (size_t)blockIdx.x * 256 + threadIdx.x;
    int tok = (int)(gid >> 8);
    float c = fmaxf(counts[tok], 1.0f);
    float4* o4 = (float4*)out;
    float4 v = o4[gid];
    v.x /= c; v.y /= c; v.z /= c; v.w /= c;
    o4[gid] = v;
    if (gid == 0) {
        float z = scal[0] / (float)(NTOK * E_);
        float aux = 0.f;
#pragma unroll
        for (int e = 0; e < E_; ++e) {
            float u = scal[1 + e] / (float)NTOK - 0.125f;
            aux += u * u;
        }
        loss_out[0] = 0.01f * aux + 0.001f * z;
    }
}

// ----------------------------------------------------------------------------
extern "C" void kernel_launch(void* const* d_in, const int* in_sizes, int n_in,
                              void* d_out, int out_size, void* d_ws, size_t ws_size,
                              hipStream_t stream) {
    const float* x  = (const float*)d_in[0];
    const float* rw = (const float*)d_in[1];
    const float* w1 = (const float*)d_in[2];
    const float* w2 = (const float*)d_in[3];
    float* out = (float*)d_out;
    char* ws = (char*)d_ws;

    float* logits = (float*)(ws + OFF_LOGITS);
    int*   tki    = (int*)(ws + OFF_TOPKI);
    float* tkw    = (float*)(ws + OFF_TOPKW);
    float* counts = (float*)(ws + OFF_COUNTS);
    float* scal   = (float*)(ws + OFF_SCAL);
    f16*   xh     = (f16*)(ws + OFF_XH);
    f16*   wt     = (f16*)(ws + OFF_WT);     // w1t, then reused as w2t
    f16*   mid    = (f16*)(ws + OFF_MID);

    hipMemsetAsync(ws + OFF_COUNTS, 0, 64u * 1024u + 64u, stream);
    hipMemsetAsync(d_out, 0, (size_t)out_size * sizeof(float), stream);

    k_cvt_x<<<NTOK * H_ / 8 / 256, 256, 0, stream>>>(x, xh);
    k_transpose<H_, I_><<<dim3(I_ / 64, H_ / 64, E_), 256, 0, stream>>>(w1, wt);
    k_router<<<NTOK / 4, 256, 0, stream>>>(x, rw, logits, scal);
    k_topk<<<NBE, 1024, 0, stream>>>(logits, tki, tkw, counts);
    k_gemm1<<<1280, 512, 0, stream>>>(xh, wt, tki, mid);
    // reuse WT region for w2t (stream-ordered after gemm1 finished reading w1t)
    k_transpose<I_, H_><<<dim3(H_ / 64, I_ / 64, E_), 256, 0, stream>>>(w2, wt);
    k_gemm2<<<1280, 512, 0, stream>>>(mid, wt, tki, tkw, out);
    k_final<<<(NTOK * H_ / 4) / 256, 256, 0, stream>>>(out, counts, scal,
                                                       out + (size_t)NTOK * H_);
}

// Round 7
// 605.403 us; speedup vs baseline: 1.3773x; 1.3773x over previous
//
#include <hip/hip_runtime.h>
#include <hip/hip_bf16.h>
#include <stdint.h>

#define B_ 4
#define S_ 2048
#define H_ 1024
#define I_ 4096
#define E_ 8
#define CAP 640
#define NTOK (B_*S_)            // 8192
#define NBE  (B_*E_)            // 32

typedef _Float16 f16;
typedef f16 f16x8 __attribute__((ext_vector_type(8)));
typedef float f32x4 __attribute__((ext_vector_type(4)));

// workspace layout (bytes)
#define OFF_LOGITS 0u                          // 65536 f32
#define OFF_TOPKI  (256u*1024u)                // 20480 int
#define OFF_TOPKW  (OFF_TOPKI + 128u*1024u)    // 20480 f32
#define OFF_COUNTS (OFF_TOPKW + 128u*1024u)    // 8192 f32
#define OFF_SCAL   (OFF_COUNTS + 64u*1024u)    // 16 f32
#define OFF_XH     (1u<<20)                    // 8192*1024 f16   (16.8 MB)
#define OFF_WT     (18u<<20)                   // 8*4096*1024 f16 (67.1 MB) — w1t then w2t (reused)
#define OFF_MID    (86u<<20)                   // 20480*4096 f16  (167.8 MB) → high-water ~254 MB

__device__ __forceinline__ void gl_lds16(const void* g, void* l) {
    __builtin_amdgcn_global_load_lds(
        (const __attribute__((address_space(1))) uint32_t*)g,
        (__attribute__((address_space(3))) uint32_t*)l, 16, 0, 0);
}

// ---------------------------------------------------------------- router ----
// NOTE: summation order is frozen — top-k selection depends on exact fp32
// logit ordering near capacity boundaries. Do not restructure this reduce.
__global__ void k_router(const float* __restrict__ x, const float* __restrict__ rw,
                         float* __restrict__ logits, float* __restrict__ scal) {
    __shared__ float rwt[E_ * H_];
    __shared__ float part[4][9];
    int tid = threadIdx.x;
    for (int i = tid; i < E_ * H_; i += 256) {
        int h = i >> 3, e = i & 7;
        rwt[e * H_ + h] = rw[i];
    }
    __syncthreads();
    int w = tid >> 6, lane = tid & 63;
    int t = blockIdx.x * 4 + w;
    const float* xr = x + (size_t)t * H_;
    float acc[E_];
#pragma unroll
    for (int e = 0; e < E_; ++e) acc[e] = 0.f;
    for (int it = 0; it < H_ / 64; ++it) {
        int h = lane + it * 64;
        float xv = xr[h];
#pragma unroll
        for (int e = 0; e < E_; ++e) acc[e] += xv * rwt[e * H_ + h];
    }
#pragma unroll
    for (int off = 32; off > 0; off >>= 1)
#pragma unroll
        for (int e = 0; e < E_; ++e) acc[e] += __shfl_down(acc[e], off);
    if (lane == 0) {
        int b = t >> 11, s = t & 2047;
        float m = acc[0];
#pragma unroll
        for (int e = 1; e < E_; ++e) m = fmaxf(m, acc[e]);
        float z = 0.f, ps = 0.f;
        float p[E_];
#pragma unroll
        for (int e = 0; e < E_; ++e) {
            logits[(size_t)((b << 3) + e) * S_ + s] = acc[e];
            z += acc[e] * acc[e];
            p[e] = expf(acc[e] - m);
            ps += p[e];
        }
        part[w][0] = z;
#pragma unroll
        for (int e = 0; e < E_; ++e) part[w][1 + e] = p[e] / ps;
    }
    __syncthreads();
    if (tid < 9) {
        float v = part[0][tid] + part[1][tid] + part[2][tid] + part[3][tid];
        atomicAdd(&scal[tid], v);
    }
}

// ----------------------------------------------------------------- top-k ----
__global__ void __launch_bounds__(1024) k_topk(const float* __restrict__ logits,
                                               int* __restrict__ tki,
                                               float* __restrict__ tkw,
                                               float* __restrict__ counts) {
    int be = blockIdx.x;
    const float* row = logits + (size_t)be * S_;
    __shared__ unsigned long long keys[S_];
    __shared__ float wpart[16];
    __shared__ float stot;
    int tid = threadIdx.x;
    for (int i = tid; i < S_; i += 1024) {
        unsigned u = __float_as_uint(row[i]);
        u = (u & 0x80000000u) ? ~u : (u | 0x80000000u);
        keys[i] = ((unsigned long long)u << 32) | (unsigned)(~i);
    }
    __syncthreads();
    for (int k = 2; k <= S_; k <<= 1) {
        for (int j = k >> 1; j > 0; j >>= 1) {
#pragma unroll
            for (int base = 0; base < S_; base += 1024) {
                int i = base + tid;
                int ixj = i ^ j;
                if (ixj > i) {
                    unsigned long long a = keys[i], b = keys[ixj];
                    bool up = ((i & k) == 0);
                    bool sw = up ? (a < b) : (a > b);
                    if (sw) { keys[i] = b; keys[ixj] = a; }
                }
            }
            __syncthreads();
        }
    }
    int idx0 = (int)(~(unsigned)(keys[0] & 0xFFFFFFFFu));
    float vmax = row[idx0];
    int myidx = 0; float ex = 0.f;
    if (tid < CAP) {
        myidx = (int)(~(unsigned)(keys[tid] & 0xFFFFFFFFu));
        ex = expf(row[myidx] - vmax);
    }
    float v = ex;
#pragma unroll
    for (int off = 32; off > 0; off >>= 1) v += __shfl_down(v, off);
    if ((tid & 63) == 0) wpart[tid >> 6] = v;
    __syncthreads();
    if (tid == 0) {
        float s = 0.f;
#pragma unroll
        for (int i = 0; i < 16; ++i) s += wpart[i];
        stot = s;
    }
    __syncthreads();
    if (tid < CAP) {
        tki[be * CAP + tid] = myidx;
        tkw[be * CAP + tid] = ex / stot;
        atomicAdd(&counts[(be >> 3) * S_ + myidx], 1.0f);
    }
}

// ------------------------------------------------------------ conversions ---
__global__ void k_cvt_x(const float* __restrict__ in, f16* __restrict__ out) {
    size_t i = ((size_t)blockIdx.x * 256 + threadIdx.x) << 3;
    float4 a = *(const float4*)(in + i);
    float4 b = *(const float4*)(in + i + 4);
    f16x8 o = { (f16)a.x, (f16)a.y, (f16)a.z, (f16)a.w,
                (f16)b.x, (f16)b.y, (f16)b.z, (f16)b.w };
    *(f16x8*)(out + i) = o;
}

// in: [E][R][C] f32 → out: [E][C][R] f16
template<int R, int C>
__global__ void __launch_bounds__(256) k_transpose(const float* __restrict__ in,
                                                   f16* __restrict__ out) {
    __shared__ f16 t[64][68];
    int e = blockIdx.z;
    const float* ine = in + (size_t)e * R * C;
    f16* oute = out + (size_t)e * R * C;
    int c0 = blockIdx.x << 6, r0 = blockIdx.y << 6;
    int tx = threadIdx.x & 15, ty = threadIdx.x >> 4;
#pragma unroll
    for (int p = 0; p < 4; ++p) {
        int r = ty + p * 16;
        float4 v = *(const float4*)(ine + (size_t)(r0 + r) * C + c0 + tx * 4);
        t[tx * 4 + 0][r] = (f16)v.x;
        t[tx * 4 + 1][r] = (f16)v.y;
        t[tx * 4 + 2][r] = (f16)v.z;
        t[tx * 4 + 3][r] = (f16)v.w;
    }
    __syncthreads();
#pragma unroll
    for (int p = 0; p < 4; ++p) {
        int c = ty + p * 16;
        *(ushort4*)(oute + (size_t)(c0 + c) * R + r0 + tx * 4) =
            *(const ushort4*)&t[c][tx * 4];
    }
}

// ============================ GEMM core geometry =============================
// EVIDENCE (R2-R6): perf tracks blocks/CU (3→2→1 blk = 302→318→410 µs);
// all in-block pipeline variants (drain/counted/3-buf/4-buf) were neutral.
// → maximize TLP: 128x128 tile, BK=64, SINGLE 32KB LDS buffer, 4 blocks/CU
//   (launch_bounds(256,4)); simple stage → sync → 32 MFMA → sync loop.
// 4 waves; wave w: wm=w>>1, wn=w&1 → 64x64 quadrant, acc[4][4] f32x4.
// Swizzle (R5-verified 0 conflicts): row = 8 chunks of 16B; chunk slot s of
// row r holds global chunk s ^ (r&7); staged via pre-swizzled global source,
// lane-linear LDS dest; read slot = (kf*4+c4) ^ (fr&7).
// Rows expert-major (expert e owns 2560 rows, 20 tiles) + per-XCD expert
// chunking (R5-verified ideal FETCH).

#define MFMA4(MI, A) \
    acc[MI][0] = __builtin_amdgcn_mfma_f32_16x16x32_f16(A, bf0, acc[MI][0], 0, 0, 0); \
    acc[MI][1] = __builtin_amdgcn_mfma_f32_16x16x32_f16(A, bf1, acc[MI][1], 0, 0, 0); \
    acc[MI][2] = __builtin_amdgcn_mfma_f32_16x16x32_f16(A, bf2, acc[MI][2], 0, 0, 0); \
    acc[MI][3] = __builtin_amdgcn_mfma_f32_16x16x32_f16(A, bf3, acc[MI][3], 0, 0, 0);

// ---------------------------------------------------------- GEMM1 (+SiLU) ---
// grid 5120 = 8 e × 20 rt × 32 ct; XCD chunk = one expert (640 blocks).
__global__ void __launch_bounds__(256, 4) k_gemm1(const f16* __restrict__ xh,
                                                  const f16* __restrict__ w1t,
                                                  const int* __restrict__ tki,
                                                  f16* __restrict__ mid) {
    __shared__ f16 As[128 * 64];   // 16 KB
    __shared__ f16 Bs[128 * 64];   // 16 KB
    int bid = blockIdx.x;
    int e = bid & 7;
    int r = bid >> 3;              // 0..639 within expert chunk
    int rt = r % 20;
    int ct = r / 20;               // 0..31
    int n0 = ct << 7;
    const f16* w1e = w1t + ((size_t)e << 22);
    int tid = threadIdx.x;
    int w = tid >> 6, l = tid & 63;
    int wm = w >> 1, wn = w & 1;

    // staging: instr i covers row r_i = i*32 + (tid>>3), dest slot tid&7,
    // global chunk gch = (tid&7) ^ (r_i & 7)  [r_i&7 == (tid>>3)&7]
    int gch = (tid & 7) ^ ((tid >> 3) & 7);
    int dstb = (tid >> 6) << 9;    // wave-uniform f16 base; HW adds lane*16B
    const f16* aS[4];
    const f16* bS[4];
#pragma unroll
    for (int i = 0; i < 4; ++i) {
        int ri = i * 32 + (tid >> 3);
        int ge = rt * 128 + ri;
        int bb = ge / 640;
        int cc = ge - bb * 640;
        int tok = tki[((bb << 3) + e) * 640 + cc];
        aS[i] = xh + ((size_t)((bb << 11) + tok) << 10) + (gch << 3);
        bS[i] = w1e + ((size_t)(n0 + ri) << 10) + (gch << 3);
    }

    int fr = l & 15, c4 = l >> 4;
    int f7 = fr & 7;
    int arow = (wm << 6) + fr;     // + mi*16
    int brow = (wn << 6) + fr;     // + ni*16
    f32x4 acc[4][4];
#pragma unroll
    for (int mi = 0; mi < 4; ++mi)
#pragma unroll
        for (int ni = 0; ni < 4; ++ni) acc[mi][ni] = (f32x4){0.f, 0.f, 0.f, 0.f};

    const int NT = H_ / 64;   // 16
    for (int t = 0; t < NT; ++t) {
        int ko = t << 6;
#pragma unroll
        for (int i = 0; i < 4; ++i) {
            gl_lds16(aS[i] + ko, As + i * 2048 + dstb);
            gl_lds16(bS[i] + ko, Bs + i * 2048 + dstb);
        }
        __syncthreads();
#pragma unroll
        for (int kf = 0; kf < 2; ++kf) {
            int sl = (((kf << 2) | c4) ^ f7) << 3;
            f16x8 bf0 = *(const f16x8*)(Bs + brow * 64 + sl);
            f16x8 bf1 = *(const f16x8*)(Bs + (brow + 16) * 64 + sl);
            f16x8 bf2 = *(const f16x8*)(Bs + (brow + 32) * 64 + sl);
            f16x8 bf3 = *(const f16x8*)(Bs + (brow + 48) * 64 + sl);
            f16x8 a0 = *(const f16x8*)(As + arow * 64 + sl);
            f16x8 a1 = *(const f16x8*)(As + (arow + 16) * 64 + sl);
            f16x8 a2 = *(const f16x8*)(As + (arow + 32) * 64 + sl);
            f16x8 a3 = *(const f16x8*)(As + (arow + 48) * 64 + sl);
            MFMA4(0, a0) MFMA4(1, a1) MFMA4(2, a2) MFMA4(3, a3)
        }
        __syncthreads();
    }

    // epilogue: SiLU + f16 store to mid. C/D: col = fr, row = c4*4 + q
    int rq4 = c4 << 2;
#pragma unroll
    for (int mi = 0; mi < 4; ++mi) {
#pragma unroll
        for (int q = 0; q < 4; ++q) {
            int row = (wm << 6) + mi * 16 + rq4 + q;
            int ge = rt * 128 + row;
            int bb = ge / 640;
            int cc = ge - bb * 640;
            size_t flat = (size_t)(((bb << 3) + e) * 640 + cc);
            f16* mrow = mid + (flat << 12) + n0 + (wn << 6) + fr;
#pragma unroll
            for (int ni = 0; ni < 4; ++ni) {
                float v = acc[mi][ni][q];
                v = v / (1.f + expf(-v));
                mrow[ni * 16] = (f16)v;
            }
        }
    }
}

// ------------------------------------------- GEMM2 + weighted atomic scatter
// grid 1280 = 8 e × 20 rt × 8 ct; XCD chunk = one expert (160 blocks).
__global__ void __launch_bounds__(256, 4) k_gemm2(const f16* __restrict__ mid,
                                                  const f16* __restrict__ w2t,
                                                  const int* __restrict__ tki,
                                                  const float* __restrict__ tkw,
                                                  float* __restrict__ out) {
    __shared__ f16 As[128 * 64];
    __shared__ f16 Bs[128 * 64];
    __shared__ int   rowOffS[128];
    __shared__ float wtsS[128];
    int bid = blockIdx.x;
    int e = bid & 7;
    int r = bid >> 3;              // 0..159
    int rt = r % 20;
    int ct = r / 20;               // 0..7
    int n0 = ct << 7;
    const f16* w2e = w2t + ((size_t)e << 22);
    int tid = threadIdx.x;
    int w = tid >> 6, l = tid & 63;
    int wm = w >> 1, wn = w & 1;

    if (tid < 128) {
        int ge = rt * 128 + tid;
        int bb = ge / 640;
        int cc = ge - bb * 640;
        int flat = ((bb << 3) + e) * 640 + cc;
        int tok = tki[flat];
        rowOffS[tid] = ((bb << 11) + tok) << 10;
        wtsS[tid] = tkw[flat];
    }

    int gch = (tid & 7) ^ ((tid >> 3) & 7);
    int dstb = (tid >> 6) << 9;
    const f16* aS[4];
    const f16* bS[4];
#pragma unroll
    for (int i = 0; i < 4; ++i) {
        int ri = i * 32 + (tid >> 3);
        int ge = rt * 128 + ri;
        int bb = ge / 640;
        int cc = ge - bb * 640;
        size_t flat = (size_t)(((bb << 3) + e) * 640 + cc);
        aS[i] = mid + (flat << 12) + (gch << 3);
        bS[i] = w2e + ((size_t)(n0 + ri) << 12) + (gch << 3);
    }

    int fr = l & 15, c4 = l >> 4;
    int f7 = fr & 7;
    int arow = (wm << 6) + fr;
    int brow = (wn << 6) + fr;
    f32x4 acc[4][4];
#pragma unroll
    for (int mi = 0; mi < 4; ++mi)
#pragma unroll
        for (int ni = 0; ni < 4; ++ni) acc[mi][ni] = (f32x4){0.f, 0.f, 0.f, 0.f};

    const int NT = I_ / 64;   // 64
    for (int t = 0; t < NT; ++t) {
        int ko = t << 6;
#pragma unroll
        for (int i = 0; i < 4; ++i) {
            gl_lds16(aS[i] + ko, As + i * 2048 + dstb);
            gl_lds16(bS[i] + ko, Bs + i * 2048 + dstb);
        }
        __syncthreads();
#pragma unroll
        for (int kf = 0; kf < 2; ++kf) {
            int sl = (((kf << 2) | c4) ^ f7) << 3;
            f16x8 bf0 = *(const f16x8*)(Bs + brow * 64 + sl);
            f16x8 bf1 = *(const f16x8*)(Bs + (brow + 16) * 64 + sl);
            f16x8 bf2 = *(const f16x8*)(Bs + (brow + 32) * 64 + sl);
            f16x8 bf3 = *(const f16x8*)(Bs + (brow + 48) * 64 + sl);
            f16x8 a0 = *(const f16x8*)(As + arow * 64 + sl);
            f16x8 a1 = *(const f16x8*)(As + (arow + 16) * 64 + sl);
            f16x8 a2 = *(const f16x8*)(As + (arow + 32) * 64 + sl);
            f16x8 a3 = *(const f16x8*)(As + (arow + 48) * 64 + sl);
            MFMA4(0, a0) MFMA4(1, a1) MFMA4(2, a2) MFMA4(3, a3)
        }
        __syncthreads();
    }

    int rq4 = c4 << 2;
#pragma unroll
    for (int mi = 0; mi < 4; ++mi) {
#pragma unroll
        for (int q = 0; q < 4; ++q) {
            int row = (wm << 6) + mi * 16 + rq4 + q;
            int ro = rowOffS[row] + n0 + (wn << 6) + fr;
            float wg = wtsS[row];
#pragma unroll
            for (int ni = 0; ni < 4; ++ni) {
                atomicAdd(&out[ro + ni * 16], acc[mi][ni][q] * wg);
            }
        }
    }
}

// ------------------------------------------------- normalize + loss ---------
__global__ void k_final(float* __restrict__ out, const float* __restrict__ counts,
                        const float* __restrict__ scal, float* __restrict__ loss_out) {
    size_t gid = (size_t)blockIdx.x * 256 + threadIdx.x;
    int tok = (int)(gid >> 8);
    float c = fmaxf(counts[tok], 1.0f);
    float4* o4 = (float4*)out;
    float4 v = o4[gid];
    v.x /= c; v.y /= c; v.z /= c; v.w /= c;
    o4[gid] = v;
    if (gid == 0) {
        float z = scal[0] / (float)(NTOK * E_);
        float aux = 0.f;
#pragma unroll
        for (int e = 0; e < E_; ++e) {
            float u = scal[1 + e] / (float)NTOK - 0.125f;
            aux += u * u;
        }
        loss_out[0] = 0.01f * aux + 0.001f * z;
    }
}

// ----------------------------------------------------------------------------
extern "C" void kernel_launch(void* const* d_in, const int* in_sizes, int n_in,
                              void* d_out, int out_size, void* d_ws, size_t ws_size,
                              hipStream_t stream) {
    const float* x  = (const float*)d_in[0];
    const float* rw = (const float*)d_in[1];
    const float* w1 = (const float*)d_in[2];
    const float* w2 = (const float*)d_in[3];
    float* out = (float*)d_out;
    char* ws = (char*)d_ws;

    float* logits = (float*)(ws + OFF_LOGITS);
    int*   tki    = (int*)(ws + OFF_TOPKI);
    float* tkw    = (float*)(ws + OFF_TOPKW);
    float* counts = (float*)(ws + OFF_COUNTS);
    float* scal   = (float*)(ws + OFF_SCAL);
    f16*   xh     = (f16*)(ws + OFF_XH);
    f16*   wt     = (f16*)(ws + OFF_WT);     // w1t, then reused as w2t
    f16*   mid    = (f16*)(ws + OFF_MID);

    hipMemsetAsync(ws + OFF_COUNTS, 0, 64u * 1024u + 64u, stream);
    hipMemsetAsync(d_out, 0, (size_t)out_size * sizeof(float), stream);

    k_cvt_x<<<NTOK * H_ / 8 / 256, 256, 0, stream>>>(x, xh);
    k_transpose<H_, I_><<<dim3(I_ / 64, H_ / 64, E_), 256, 0, stream>>>(w1, wt);
    k_router<<<NTOK / 4, 256, 0, stream>>>(x, rw, logits, scal);
    k_topk<<<NBE, 1024, 0, stream>>>(logits, tki, tkw, counts);
    k_gemm1<<<5120, 256, 0, stream>>>(xh, wt, tki, mid);
    // reuse WT region for w2t (stream-ordered after gemm1 finished reading w1t)
    k_transpose<I_, H_><<<dim3(H_ / 64, I_ / 64, E_), 256, 0, stream>>>(w2, wt);
    k_gemm2<<<1280, 256, 0, stream>>>(mid, wt, tki, tkw, out);
    k_final<<<(NTOK * H_ / 4) / 256, 256, 0, stream>>>(out, counts, scal,
                                                       out + (size_t)NTOK * H_);
}